// Round 21
// baseline (92.090 us; speedup 1.0000x reference)
//
#include <hip/hip_runtime.h>

#define D     160
#define D2    (D * D)
#define D3    (D * D * D)
#define NB    4
#define TL    4                     // xy tile edge
#define ZSL   32                    // z slab
#define ZWIN  40                    // z slots [zl-4 .. zl+35]
#define WINX  12                    // x slots [xt-4 .. xt+7]
#define RING  28                    // 16 read + 8 stage-ahead + 4 spacer
#define PLANE 484                   // 480 used + 4 pad: slot adds 4*slot mod 32
                                    // bank phase (480 was 0 mod 32 -> y gave NO
                                    // bank entropy -> systematic conflicts)
#define LDSF  (RING * PLANE)        // 13552 floats = 54.2 KB -> 3 WG/CU
#define TPB   256                   // 4 waves
#define NWAVE 4
#define TPDX  (D / TL)              // 40
#define TPDZ  (D / ZSL)             // 5
#define NRUN  4
#define NBLK  (NB * TPDX * TPDZ * NRUN)   // 3200

typedef float f32x2 __attribute__((ext_vector_type(2)));
typedef int   i32x2 __attribute__((ext_vector_type(2)));

struct AState {
    f32x2 wx2, wy2, wz2;
    int ba[2], bc[2];
    unsigned flags, shb;
    f32x2 fb00[2], fb01[2], fb10[2], fb11[2];
};

__device__ __forceinline__ void phaseA(
    const float* __restrict__ vol,
    float xgf, float ygf, float zgf,
    int xwb, int ywb, int zwb, int su,
    f32x2 q0, f32x2 q1, f32x2 q2, AState& S)
{
    const f32x2 zero2 = {0.0f, 0.0f};
    const f32x2 max2  = {(float)(D - 1), (float)(D - 1)};
    f32x2 dx = {q0.x, q1.y};
    f32x2 dy = {q0.y, q2.x};
    f32x2 dz = {q1.x, q2.y};
    f32x2 xg2 = {xgf, xgf};
    f32x2 yg2 = {ygf, ygf};
    f32x2 zg2 = {zgf, zgf + 1.0f};

    f32x2 fx2 = __builtin_elementwise_min(
                    __builtin_elementwise_max(xg2 + dx, zero2), max2);
    f32x2 fy2 = __builtin_elementwise_min(
                    __builtin_elementwise_max(yg2 + dy, zero2), max2);
    f32x2 fz2 = __builtin_elementwise_min(
                    __builtin_elementwise_max(zg2 + dz, zero2), max2);

    i32x2 X0 = __builtin_convertvector(fx2, i32x2);   // trunc == floor (>=0)
    i32x2 Y0 = __builtin_convertvector(fy2, i32x2);
    i32x2 Z0 = __builtin_convertvector(fz2, i32x2);
    S.wx2 = fx2 - __builtin_convertvector(X0, f32x2);
    S.wy2 = fy2 - __builtin_convertvector(Y0, f32x2);
    S.wz2 = fz2 - __builtin_convertvector(Z0, f32x2);

    S.flags = 0; S.shb = 0;
#pragma unroll
    for (int j = 0; j < 2; ++j) {
        S.fb00[j] = f32x2{0, 0}; S.fb01[j] = f32x2{0, 0};
        S.fb10[j] = f32x2{0, 0}; S.fb11[j] = f32x2{0, 0};
        int x0 = X0[j], y0 = Y0[j], z0 = Z0[j];
        int sx0 = x0 - xwb, sy0 = y0 - ywb, sz0 = z0 - zwb;
        bool inWin = ((unsigned)sx0 <= 10u) & ((unsigned)sy0 <= 10u) &
                     ((unsigned)sz0 <= 38u);
        S.flags |= (unsigned)inWin << j;
        int csx = min(max(sx0, 0), 10);   // v_med3_i32, garbage-safe
        int csy = min(max(sy0, 0), 10);
        int csz = min(max(sz0, 0), 38);
        int t0 = su + csy; if (t0 >= RING) t0 -= RING;   // slot of y0
        int t1 = t0 + 1;   if (t1 == RING) t1 = 0;       // slot of y0+1
        S.ba[j] = t0 * PLANE + csx * ZWIN + csz;         // max 13505 + 41 < 13552
        S.bc[j] = t1 * PLANE + csx * ZWIN + csz;
        if (!inWin) {                   // very rare (halo 4): exact global path
            int x1 = min(x0 + 1, D - 1);
            int y1 = min(y0 + 1, D - 1);
            int zc = min(z0, D - 2);
            S.shb |= (unsigned)(z0 > zc) << j;    // z0==159 -> wz==0
            S.fb00[j] = *(const f32x2*)(vol + x0 * D2 + y0 * D + zc);
            S.fb01[j] = *(const f32x2*)(vol + x0 * D2 + y1 * D + zc);
            S.fb10[j] = *(const f32x2*)(vol + x1 * D2 + y0 * D + zc);
            S.fb11[j] = *(const f32x2*)(vol + x1 * D2 + y1 * D + zc);
        }
    }
}

__device__ __forceinline__ f32x2 phaseB(const float* __restrict__ buf,
                                        const AState& S)
{
    const f32x2 one2 = {1.0f, 1.0f};
    float a0s[2], a1s[2], c0s[2], c1s[2], e0s[2], e1s[2], g0s[2], g1s[2];
#pragma unroll
    for (int j = 0; j < 2; ++j) {
        a0s[j] = buf[S.ba[j]];          a1s[j] = buf[S.ba[j] + 1];
        c0s[j] = buf[S.bc[j]];          c1s[j] = buf[S.bc[j] + 1];
        e0s[j] = buf[S.ba[j] + ZWIN];   e1s[j] = buf[S.ba[j] + ZWIN + 1];
        g0s[j] = buf[S.bc[j] + ZWIN];   g1s[j] = buf[S.bc[j] + ZWIN + 1];
        if (!((S.flags >> j) & 1)) {
            bool sh = (S.shb >> j) & 1;
            a0s[j] = sh ? S.fb00[j].y : S.fb00[j].x;  a1s[j] = S.fb00[j].y;
            c0s[j] = sh ? S.fb01[j].y : S.fb01[j].x;  c1s[j] = S.fb01[j].y;
            e0s[j] = sh ? S.fb10[j].y : S.fb10[j].x;  e1s[j] = S.fb10[j].y;
            g0s[j] = sh ? S.fb11[j].y : S.fb11[j].x;  g1s[j] = S.fb11[j].y;
        }
    }
    f32x2 A0 = {a0s[0], a0s[1]}, A1 = {a1s[0], a1s[1]};
    f32x2 C0 = {c0s[0], c0s[1]}, C1 = {c1s[0], c1s[1]};
    f32x2 E0 = {e0s[0], e0s[1]}, E1 = {e1s[0], e1s[1]};
    f32x2 G0 = {g0s[0], g0s[1]}, G1 = {g1s[0], g1s[1]};

    f32x2 ux2 = one2 - S.wx2, uy2 = one2 - S.wy2, uz2 = one2 - S.wz2;
    return (A0 * uz2 + A1 * S.wz2) * (ux2 * uy2)
         + (C0 * uz2 + C1 * S.wz2) * (ux2 * S.wy2)
         + (E0 * uz2 + E1 * S.wz2) * (S.wx2 * uy2)
         + (G0 * uz2 + G1 * S.wz2) * (S.wx2 * S.wy2);
}

__global__ __launch_bounds__(TPB) void warp_kernel(
    const float* __restrict__ ddf,     // [B, D, D, D, 3]
    const float* __restrict__ image,   // [B, D, D, D]
    float* __restrict__ out)           // [B, D, D, D]
{
    extern __shared__ float buf[];     // RING * PLANE floats (54.2 KB)

    const int tid  = threadIdx.x;
    const int w    = tid >> 6;             // wave 0..3
    const int lane = tid & 63;
    const int row  = tid >> 4;             // 0..15 (4x * 4y)
    const int zch  = tid & 15;             // 0..15
    const int rx   = row >> 2, ry = row & 3, zbl = zch * 2;

    // ---- block decode (XCD-chunked; 3200 % 8 == 0 -> bijective) ----
    int g    = blockIdx.x;
    int gx8  = (g & 7) * (NBLK / 8) + (g >> 3);
    int yrun = gx8 & 3;
    int t    = gx8 >> 2;
    int zi   = t % TPDZ;  t /= TPDZ;
    int xi   = t % TPDX;
    int b    = t / TPDX;

    const int yt0    = yrun * 40;          // 0,40,80,120
    const int xt     = xi * TL, zl = zi * ZSL;
    const int xwb    = xt - 4,  zwb = zl - 4;
    const int volofs = b * D3;
    const float* vol = image + volofs;

    // ---- per-lane stage constants k = 0..1 (block-fixed x/z source) ----
    int pfix[2];
#pragma unroll
    for (int k = 0; k < 2; ++k) {
        int f  = k * 256 + lane * 4;       // multiple of 4 -> 16B aligned
        int sx = f / ZWIN;
        int zo = f - sx * ZWIN;            // multiple of 4 (40 % 4 == 0)
        int srcx = min(max(xwb + sx, 0), D - 1);
        int srcz = min(max(zwb + zo, 0), D - 4);
        pfix[k] = volofs + srcx * D2 + srcz;
    }

    // slot(p) = (p + 4) % RING; su = slot(ywb) = yt0 % 28 (wave-uniform)
    int su  = yt0 % RING;                  // 0,12,24,8 per yrun
    int ywb = yt0 - 4;

    // voxel cursor
    int   vb  = volofs + (xt + rx) * D2 + (yt0 + ry) * D + (zl + zbl);
    float ygf = (float)(yt0 + ry);
    const float xgf = (float)(xt + rx);
    const float zgf = (float)(zl + zbl);

    const int kk = w & 1;                  // stage chunk index (wave-uniform)

    // ---- prologue: stage 16 planes [ywb .. ywb+15] = 32 jobs; ddf(0,1) ----
#pragma unroll
    for (int m = 0; m < 8; ++m) {
        int L  = w + m * NWAVE;            // 0..31
        int pi = L >> 1, k = L & 1;        // k == w&1
        int p  = ywb + pi;
        int srcy = max(p, 0);              // p <= yt0+11 <= 131 < 159
        int slot = su + pi; if (slot >= RING) slot -= RING;
        if (k == 0 || lane < 56) {         // chunk 1 covers floats 256..479
            const float* gp = image + pfix[k] + srcy * D;
            __builtin_amdgcn_global_load_lds(
                (const __attribute__((address_space(1))) void*)gp,
                (__attribute__((address_space(3))) void*)(buf + slot * PLANE + k * 256),
                16, 0, 0);
        }
    }
    f32x2 qa0, qa1, qa2, qb0, qb1, qb2;
    f32x2 na0 = {0,0}, na1 = {0,0}, na2 = {0,0};
    f32x2 nb0 = {0,0}, nb1 = {0,0}, nb2 = {0,0};
    {
        const float* p = ddf + (size_t)vb * 3;
        qa0 = __builtin_nontemporal_load((const f32x2*)p);
        qa1 = __builtin_nontemporal_load((const f32x2*)(p + 2));
        qa2 = __builtin_nontemporal_load((const f32x2*)(p + 4));
        const float* p2 = ddf + (size_t)(vb + TL * D) * 3;
        qb0 = __builtin_nontemporal_load((const f32x2*)p2);
        qb1 = __builtin_nontemporal_load((const f32x2*)(p2 + 2));
        qb2 = __builtin_nontemporal_load((const f32x2*)(p2 + 4));
    }
    asm volatile("s_waitcnt vmcnt(0)" ::: "memory");
    __builtin_amdgcn_sched_barrier(0);
    __builtin_amdgcn_s_barrier();
    __builtin_amdgcn_sched_barrier(0);

#pragma unroll 1
    for (int d = 0; d < 5; ++d) {          // 5 double-iterations = 10 tiles
        const bool more = (d < 4);

        // ---- stage(d) at TOP: planes [ywb+16..23] -> slots su+16..23.
        //      WAR-safe: issued after end-barrier(d-1); writes only
        //      out-of-window slots. Consumed in phase B of iter d+1 ----
        if (more) {
#pragma unroll
            for (int s = 0; s < 4; ++s) {
                int pi = (w >> 1) + s * 2;          // 0..7
                int p  = ywb + 16 + pi;
                int srcy = min(p, D - 1);
                int slot = su + 16 + pi; if (slot >= RING) slot -= RING;
                if (kk == 0 || lane < 56) {
                    const float* gp = image + pfix[kk] + srcy * D;
                    __builtin_amdgcn_global_load_lds(
                        (const __attribute__((address_space(1))) void*)gp,
                        (__attribute__((address_space(3))) void*)(buf + slot * PLANE + kk * 256),
                        16, 0, 0);
                }
            }
        }
        __builtin_amdgcn_sched_barrier(0);

        // ---- phase A for both tiles (two independent chains) ----
        int su4 = su + 4; if (su4 >= RING) su4 -= RING;
        AState Sa, Sb;
        phaseA(vol, xgf, ygf,        zgf, xwb, ywb,     zwb, su,  qa0, qa1, qa2, Sa);
        phaseA(vol, xgf, ygf + 4.0f, zgf, xwb, ywb + 4, zwb, su4, qb0, qb1, qb2, Sb);
        __builtin_amdgcn_sched_barrier(0);

        // ---- ddf(d+1) ----
        if (more) {
            const float* p = ddf + (size_t)(vb + 8 * D) * 3;
            na0 = __builtin_nontemporal_load((const f32x2*)p);
            na1 = __builtin_nontemporal_load((const f32x2*)(p + 2));
            na2 = __builtin_nontemporal_load((const f32x2*)(p + 4));
            const float* p2 = ddf + (size_t)(vb + 12 * D) * 3;
            nb0 = __builtin_nontemporal_load((const f32x2*)p2);
            nb1 = __builtin_nontemporal_load((const f32x2*)(p2 + 2));
            nb2 = __builtin_nontemporal_load((const f32x2*)(p2 + 4));
        }
        __builtin_amdgcn_sched_barrier(0);

        // ---- phase B for both tiles + stores ----
        f32x2 ra = phaseB(buf, Sa);
        f32x2 rb = phaseB(buf, Sb);
        __builtin_nontemporal_store(ra, (f32x2*)(out + vb));
        __builtin_nontemporal_store(rb, (f32x2*)(out + vb + 4 * D));
        __builtin_amdgcn_sched_barrier(0);

        // ---- single gate+barrier: force stage(d) (+fb) retired, publish;
        //      keep ddf(6) + stores(2) in flight ----
        if (more) {
            asm volatile("s_waitcnt vmcnt(8)" ::: "memory");
            __builtin_amdgcn_sched_barrier(0);
            __builtin_amdgcn_s_barrier();
            __builtin_amdgcn_sched_barrier(0);

            qa0 = na0; qa1 = na1; qa2 = na2;
            qb0 = nb0; qb1 = nb1; qb2 = nb2;
            vb += 8 * D; ygf += 8.0f; ywb += 8;
            su += 8; if (su >= RING) su -= RING;
        }
    }
}

extern "C" void kernel_launch(void* const* d_in, const int* in_sizes, int n_in,
                              void* d_out, int out_size, void* d_ws, size_t ws_size,
                              hipStream_t stream) {
    const float* ddf   = (const float*)d_in[0];
    const float* image = (const float*)d_in[1];
    float* out = (float*)d_out;

    warp_kernel<<<NBLK, TPB, LDSF * sizeof(float), stream>>>(ddf, image, out);
}

// Round 22
// 81.672 us; speedup vs baseline: 1.1276x; 1.1276x over previous
//
#include <hip/hip_runtime.h>

#define D     160
#define D2    (D * D)
#define D3    (D * D * D)
#define NB    4
#define TL    4                     // xy tile edge
#define ZSL   32                    // z slab
#define ZWIN  40                    // z slots [zl-4 .. zl+35]
#define WINX  12                    // x slots [xt-4 .. xt+7]
#define RING  28                    // 16 read + 8 stage-ahead + 4 spacer
#define PLANE 480                   // WINX * ZWIN floats (exact; r20 pad reverted)
#define LDSF  (RING * PLANE)        // 13440 floats = 52.5 KB -> 3 WG/CU
#define TPB   256                   // 4 waves
#define NWAVE 4
#define TPDX  (D / TL)              // 40
#define TPDZ  (D / ZSL)             // 5
#define NRUN  4
#define NBLK  (NB * TPDX * TPDZ * NRUN)   // 3200

typedef float f32x2 __attribute__((ext_vector_type(2)));
typedef int   i32x2 __attribute__((ext_vector_type(2)));

struct AState {                      // lean: no fb prefetch arrays (r20 lesson:
    f32x2 wx2, wy2, wz2;             // VGPR pressure is the live constraint)
    int ba[2], bc[2];
    int pk[2];                       // packed x0|y0<<8|z0<<16 for lazy fallback
    unsigned flags;
};

__device__ __forceinline__ void phaseA(
    float xgf, float ygf, float zgf,
    int xwb, int ywb, int zwb, int su,
    f32x2 q0, f32x2 q1, f32x2 q2, AState& S)
{
    const f32x2 zero2 = {0.0f, 0.0f};
    const f32x2 max2  = {(float)(D - 1), (float)(D - 1)};
    f32x2 dx = {q0.x, q1.y};
    f32x2 dy = {q0.y, q2.x};
    f32x2 dz = {q1.x, q2.y};
    f32x2 xg2 = {xgf, xgf};
    f32x2 yg2 = {ygf, ygf};
    f32x2 zg2 = {zgf, zgf + 1.0f};

    f32x2 fx2 = __builtin_elementwise_min(
                    __builtin_elementwise_max(xg2 + dx, zero2), max2);
    f32x2 fy2 = __builtin_elementwise_min(
                    __builtin_elementwise_max(yg2 + dy, zero2), max2);
    f32x2 fz2 = __builtin_elementwise_min(
                    __builtin_elementwise_max(zg2 + dz, zero2), max2);

    i32x2 X0 = __builtin_convertvector(fx2, i32x2);   // trunc == floor (>=0)
    i32x2 Y0 = __builtin_convertvector(fy2, i32x2);
    i32x2 Z0 = __builtin_convertvector(fz2, i32x2);
    S.wx2 = fx2 - __builtin_convertvector(X0, f32x2);
    S.wy2 = fy2 - __builtin_convertvector(Y0, f32x2);
    S.wz2 = fz2 - __builtin_convertvector(Z0, f32x2);

    S.flags = 0;
#pragma unroll
    for (int j = 0; j < 2; ++j) {
        int x0 = X0[j], y0 = Y0[j], z0 = Z0[j];
        int sx0 = x0 - xwb, sy0 = y0 - ywb, sz0 = z0 - zwb;
        bool inWin = ((unsigned)sx0 <= 10u) & ((unsigned)sy0 <= 10u) &
                     ((unsigned)sz0 <= 38u);
        S.flags |= (unsigned)inWin << j;
        int csx = min(max(sx0, 0), 10);   // v_med3_i32, garbage-safe
        int csy = min(max(sy0, 0), 10);
        int csz = min(max(sz0, 0), 38);
        int t0 = su + csy; if (t0 >= RING) t0 -= RING;   // slot of y0
        int t1 = t0 + 1;   if (t1 == RING) t1 = 0;       // slot of y0+1
        S.ba[j] = t0 * PLANE + csx * ZWIN + csz;         // max 13398; +41 fits
        S.bc[j] = t1 * PLANE + csx * ZWIN + csz;
        S.pk[j] = x0 | (y0 << 8) | (z0 << 16);           // for lazy fallback
    }
}

__device__ __forceinline__ f32x2 phaseB(const float* __restrict__ buf,
                                        const float* __restrict__ vol,
                                        const AState& S)
{
    const f32x2 one2 = {1.0f, 1.0f};
    float a0s[2], a1s[2], c0s[2], c1s[2], e0s[2], e1s[2], g0s[2], g1s[2];
#pragma unroll
    for (int j = 0; j < 2; ++j) {
        a0s[j] = buf[S.ba[j]];          a1s[j] = buf[S.ba[j] + 1];
        c0s[j] = buf[S.bc[j]];          c1s[j] = buf[S.bc[j] + 1];
        e0s[j] = buf[S.ba[j] + ZWIN];   e1s[j] = buf[S.ba[j] + ZWIN + 1];
        g0s[j] = buf[S.bc[j] + ZWIN];   g1s[j] = buf[S.bc[j] + ZWIN + 1];
        if (!((S.flags >> j) & 1)) {    // lazy fallback: P ~ 1e-4/voxel,
            int x0 = S.pk[j] & 255;     // wave-level execz skip ~98.7% of iters
            int y0 = (S.pk[j] >> 8) & 255;
            int z0 = S.pk[j] >> 16;
            int x1 = min(x0 + 1, D - 1);
            int y1 = min(y0 + 1, D - 1);
            int zc = min(z0, D - 2);
            bool sh = z0 > zc;          // z0==159 -> wz==0
            f32x2 f00 = *(const f32x2*)(vol + x0 * D2 + y0 * D + zc);
            f32x2 f01 = *(const f32x2*)(vol + x0 * D2 + y1 * D + zc);
            f32x2 f10 = *(const f32x2*)(vol + x1 * D2 + y0 * D + zc);
            f32x2 f11 = *(const f32x2*)(vol + x1 * D2 + y1 * D + zc);
            a0s[j] = sh ? f00.y : f00.x;  a1s[j] = f00.y;
            c0s[j] = sh ? f01.y : f01.x;  c1s[j] = f01.y;
            e0s[j] = sh ? f10.y : f10.x;  e1s[j] = f10.y;
            g0s[j] = sh ? f11.y : f11.x;  g1s[j] = f11.y;
        }
    }
    f32x2 A0 = {a0s[0], a0s[1]}, A1 = {a1s[0], a1s[1]};
    f32x2 C0 = {c0s[0], c0s[1]}, C1 = {c1s[0], c1s[1]};
    f32x2 E0 = {e0s[0], e0s[1]}, E1 = {e1s[0], e1s[1]};
    f32x2 G0 = {g0s[0], g0s[1]}, G1 = {g1s[0], g1s[1]};

    f32x2 ux2 = one2 - S.wx2, uy2 = one2 - S.wy2, uz2 = one2 - S.wz2;
    return (A0 * uz2 + A1 * S.wz2) * (ux2 * uy2)
         + (C0 * uz2 + C1 * S.wz2) * (ux2 * S.wy2)
         + (E0 * uz2 + E1 * S.wz2) * (S.wx2 * uy2)
         + (G0 * uz2 + G1 * S.wz2) * (S.wx2 * S.wy2);
}

__global__ __launch_bounds__(TPB) void warp_kernel(
    const float* __restrict__ ddf,     // [B, D, D, D, 3]
    const float* __restrict__ image,   // [B, D, D, D]
    float* __restrict__ out)           // [B, D, D, D]
{
    extern __shared__ float buf[];     // RING * PLANE floats (52.5 KB)

    const int tid  = threadIdx.x;
    const int w    = tid >> 6;             // wave 0..3
    const int lane = tid & 63;
    const int row  = tid >> 4;             // 0..15 (4x * 4y)
    const int zch  = tid & 15;             // 0..15
    const int rx   = row >> 2, ry = row & 3, zbl = zch * 2;

    // ---- block decode (XCD-chunked; 3200 % 8 == 0 -> bijective) ----
    int g    = blockIdx.x;
    int gx8  = (g & 7) * (NBLK / 8) + (g >> 3);
    int yrun = gx8 & 3;
    int t    = gx8 >> 2;
    int zi   = t % TPDZ;  t /= TPDZ;
    int xi   = t % TPDX;
    int b    = t / TPDX;

    const int yt0    = yrun * 40;          // 0,40,80,120
    const int xt     = xi * TL, zl = zi * ZSL;
    const int xwb    = xt - 4,  zwb = zl - 4;
    const int volofs = b * D3;
    const float* vol = image + volofs;

    // ---- per-lane stage constants k = 0..1 (block-fixed x/z source) ----
    int pfix[2];
#pragma unroll
    for (int k = 0; k < 2; ++k) {
        int f  = k * 256 + lane * 4;       // multiple of 4 -> 16B aligned
        int sx = f / ZWIN;
        int zo = f - sx * ZWIN;            // multiple of 4 (40 % 4 == 0)
        int srcx = min(max(xwb + sx, 0), D - 1);
        int srcz = min(max(zwb + zo, 0), D - 4);
        pfix[k] = volofs + srcx * D2 + srcz;
    }

    // slot(p) = (p + 4) % RING; su = slot(ywb) = yt0 % 28 (wave-uniform)
    int su  = yt0 % RING;                  // 0,12,24,8 per yrun
    int ywb = yt0 - 4;

    // voxel cursor
    int   vb  = volofs + (xt + rx) * D2 + (yt0 + ry) * D + (zl + zbl);
    float ygf = (float)(yt0 + ry);
    const float xgf = (float)(xt + rx);
    const float zgf = (float)(zl + zbl);

    const int kk = w & 1;                  // stage chunk index (wave-uniform)

    // ---- prologue: stage 16 planes [ywb .. ywb+15] = 32 jobs; ddf(0,1) ----
#pragma unroll
    for (int m = 0; m < 8; ++m) {
        int L  = w + m * NWAVE;            // 0..31
        int pi = L >> 1, k = L & 1;        // k == w&1
        int p  = ywb + pi;
        int srcy = max(p, 0);              // p <= yt0+11 <= 131 < 159
        int slot = su + pi; if (slot >= RING) slot -= RING;
        if (k == 0 || lane < 56) {         // chunk 1 covers floats 256..479
            const float* gp = image + pfix[k] + srcy * D;
            __builtin_amdgcn_global_load_lds(
                (const __attribute__((address_space(1))) void*)gp,
                (__attribute__((address_space(3))) void*)(buf + slot * PLANE + k * 256),
                16, 0, 0);
        }
    }
    f32x2 qa0, qa1, qa2, qb0, qb1, qb2;
    f32x2 na0 = {0,0}, na1 = {0,0}, na2 = {0,0};
    f32x2 nb0 = {0,0}, nb1 = {0,0}, nb2 = {0,0};
    {
        const float* p = ddf + (size_t)vb * 3;
        qa0 = __builtin_nontemporal_load((const f32x2*)p);
        qa1 = __builtin_nontemporal_load((const f32x2*)(p + 2));
        qa2 = __builtin_nontemporal_load((const f32x2*)(p + 4));
        const float* p2 = ddf + (size_t)(vb + TL * D) * 3;
        qb0 = __builtin_nontemporal_load((const f32x2*)p2);
        qb1 = __builtin_nontemporal_load((const f32x2*)(p2 + 2));
        qb2 = __builtin_nontemporal_load((const f32x2*)(p2 + 4));
    }
    asm volatile("s_waitcnt vmcnt(0)" ::: "memory");
    __builtin_amdgcn_sched_barrier(0);
    __builtin_amdgcn_s_barrier();
    __builtin_amdgcn_sched_barrier(0);

#pragma unroll 1
    for (int d = 0; d < 5; ++d) {          // 5 double-iterations = 10 tiles
        const bool more = (d < 4);

        // ---- stage(d) at TOP: planes [ywb+16..23] -> slots su+16..23.
        //      WAR-safe: after end-barrier(d-1); writes only out-of-window
        //      slots. Consumed in phase B of iter d+1 -> full-iter cover ----
        if (more) {
#pragma unroll
            for (int s = 0; s < 4; ++s) {
                int pi = (w >> 1) + s * 2;          // 0..7
                int p  = ywb + 16 + pi;
                int srcy = min(p, D - 1);
                int slot = su + 16 + pi; if (slot >= RING) slot -= RING;
                if (kk == 0 || lane < 56) {
                    const float* gp = image + pfix[kk] + srcy * D;
                    __builtin_amdgcn_global_load_lds(
                        (const __attribute__((address_space(1))) void*)gp,
                        (__attribute__((address_space(3))) void*)(buf + slot * PLANE + kk * 256),
                        16, 0, 0);
                }
            }
        }
        __builtin_amdgcn_sched_barrier(0);

        // ---- phase A for both tiles (two independent chains, lean state) ----
        int su4 = su + 4; if (su4 >= RING) su4 -= RING;
        AState Sa, Sb;
        phaseA(xgf, ygf,        zgf, xwb, ywb,     zwb, su,  qa0, qa1, qa2, Sa);
        phaseA(xgf, ygf + 4.0f, zgf, xwb, ywb + 4, zwb, su4, qb0, qb1, qb2, Sb);
        __builtin_amdgcn_sched_barrier(0);

        // ---- ddf(d+1) ----
        if (more) {
            const float* p = ddf + (size_t)(vb + 8 * D) * 3;
            na0 = __builtin_nontemporal_load((const f32x2*)p);
            na1 = __builtin_nontemporal_load((const f32x2*)(p + 2));
            na2 = __builtin_nontemporal_load((const f32x2*)(p + 4));
            const float* p2 = ddf + (size_t)(vb + 12 * D) * 3;
            nb0 = __builtin_nontemporal_load((const f32x2*)p2);
            nb1 = __builtin_nontemporal_load((const f32x2*)(p2 + 2));
            nb2 = __builtin_nontemporal_load((const f32x2*)(p2 + 4));
        }
        __builtin_amdgcn_sched_barrier(0);

        // ---- phase B for both tiles + stores (fallback lazy, execz-skip) ----
        f32x2 ra = phaseB(buf, vol, Sa);
        f32x2 rb = phaseB(buf, vol, Sb);
        __builtin_nontemporal_store(ra, (f32x2*)(out + vb));
        __builtin_nontemporal_store(rb, (f32x2*)(out + vb + 4 * D));
        __builtin_amdgcn_sched_barrier(0);

        // ---- single gate+barrier: force stage(d) retired, publish;
        //      keep ddf(6) + stores(2) in flight ----
        if (more) {
            asm volatile("s_waitcnt vmcnt(8)" ::: "memory");
            __builtin_amdgcn_sched_barrier(0);
            __builtin_amdgcn_s_barrier();
            __builtin_amdgcn_sched_barrier(0);

            qa0 = na0; qa1 = na1; qa2 = na2;
            qb0 = nb0; qb1 = nb1; qb2 = nb2;
            vb += 8 * D; ygf += 8.0f; ywb += 8;
            su += 8; if (su >= RING) su -= RING;
        }
    }
}

extern "C" void kernel_launch(void* const* d_in, const int* in_sizes, int n_in,
                              void* d_out, int out_size, void* d_ws, size_t ws_size,
                              hipStream_t stream) {
    const float* ddf   = (const float*)d_in[0];
    const float* image = (const float*)d_in[1];
    float* out = (float*)d_out;

    warp_kernel<<<NBLK, TPB, LDSF * sizeof(float), stream>>>(ddf, image, out);
}